// Round 2
// baseline (100.714 us; speedup 1.0000x reference)
//
#include <hip/hip_runtime.h>
#include <math.h>

// Problem constants (from reference / setup_inputs)
#define N_ROIS   32
#define N_CAT    (N_ROIS * 9)      // 288 cat_rois rows
#define C_FEAT   256
#define H_FEAT   40
#define W_FEAT   40
#define P_FEAT   (H_FEAT * W_FEAT) // 1600 pixels
#define PH       7
#define PW       7
#define SCALE    0.0625f
#define MIN_SIZE 16.0f
#define CELLS    (PH * PW)                 // 49
#define POOL_PER_BOX (C_FEAT * CELLS)      // 12544
#define OUT_POOL_ELEMS ((size_t)N_CAT * POOL_PER_BOX)  // 3,612,672

// Fused-kernel geometry: block = (box, channel-quarter)
#define CH_G      64                        // channels per block
#define NCHG      (C_FEAT / CH_G)           // 4
#define POOL_BLKS (N_CAT * NCHG)            // 1152 == 8 * 144 (XCD-bijective)
#define THREADS   448                       // 64 ch x 7 pooled rows
#define WROWS     14                        // max window rows (bsh <= 2)
#define WCOLS     14                        // max window cols (bsw <= 2)
#define WSTRIDE   197                       // per-channel LDS stride (odd ->
                                            // lane-stride 197 mod 32 = 5,
                                            // gcd(5,32)=1: conflict-free)

// ---------------------------------------------------------------------------
// Single fused kernel. No workspace, no transpose, no inter-kernel dependency.
//
// Per block (box b, channel-quarter cg):
//  1. stage 32x5 rois into LDS (broadcast reads thereafter).
//  2. wave 0 recomputes box b's context-anchor + IoU labeling REDUNDANTLY
//     (32-iter loop, ~0.2us) -> box coords to LDS; cg==0/tid==0 also writes
//     the cat_rois output row. This removes the prep->pool launch dependency.
//  3. stage the box's feature window (<=14x14 x 64 ch = 50KB) from native
//     NCHW into LDS. Load index e: x fastest -> global reads are 56B
//     contiguous runs (a wave touches ~6 lines vs 64 for naive NCHW).
//     LDS layout win[ch][197]: writes are x-contiguous (conflict-free),
//     compute reads are ch-strided (stride 197 floats, odd -> conflict-free).
//  4. proven inner loop per (channel, pooled-row): 14 batched window loads,
//     branch-free predicated maxes, kmax=2j+2 pruning (valid for bsw<=2).
//  5. direct stores (the round -1 pattern; LDS-staged stores measured neutral).
//
// Occupancy: 51KB LDS -> 3 blocks/CU x 7 waves = 21 waves/CU.
// ---------------------------------------------------------------------------
__global__ __launch_bounds__(THREADS, 4) void
fused_pool_kernel(const float* __restrict__ f,
                  const float* __restrict__ rois,
                  const int* __restrict__ hh_p,
                  const int* __restrict__ hw_p,
                  float* __restrict__ out) {
    __shared__ float R[N_ROIS * 5];                    // 640 B
    __shared__ float BX[4];                            // box coords broadcast
    __shared__ __align__(16) float win[CH_G * WSTRIDE]; // 50,432 B

    const int bid = blockIdx.x;
    // XCD-bijective swizzle (1152 = 8*144): XCD k gets s in [k*144,(k+1)*144)
    const int s   = (bid & 7) * (POOL_BLKS / 8) + (bid >> 3);
    const int b   = s >> 2;            // box 0..287 (4 ch-quarters adjacent)
    const int cg  = s & 3;             // channel quarter
    const int tid = threadIdx.x;

    if (tid < N_ROIS * 5) R[tid] = rois[tid];
    __syncthreads();

    // ---- step 2: box coords (wave 0, redundant across lanes) ----
    if (tid < 64) {
        const int n  = b / 9;
        const int jj = b % 9;
        const float x1 = R[n * 5 + 1], y1 = R[n * 5 + 2];
        const float x2 = R[n * 5 + 3], y2 = R[n * 5 + 4];
        float bx1, by1, bx2, by2;

        if (jj == 0) {                 // parent roi row
            bx1 = x1; by1 = y1; bx2 = x2; by2 = y2;
            if (tid == 0 && cg == 0) {
                float* rr = out + OUT_POOL_ELEMS + (size_t)b * 5;
                #pragma unroll
                for (int t = 0; t < 5; ++t) rr[t] = R[n * 5 + t];
            }
        } else {
            const int j = jj - 1;
            const int m = (j < 4) ? j : j + 1;   // skip center of 3x3
            const int r  = m / 3;
            const int cc = m % 3;
            const float w = x2 - x1, h = y2 - y1;
            const float cx = x1 + w * ((float)cc - 0.5f);
            const float cy = y1 + h * ((float)r  - 0.5f);
            bx1 = cx - w * 0.25f;
            by1 = cy - h * 0.25f;
            bx2 = cx + w * 0.25f;
            by2 = cy + h * 0.25f;
            const float bw = bx2 - bx1 + 1.0f;
            const float bh = by2 - by1 + 1.0f;
            const float hh = (float)(*hh_p);
            const float hw = (float)(*hw_p);
            const bool invalid = (bx1 < 0.0f) || (by1 < 0.0f) ||
                                 (bx2 >= hw) || (by2 >= hh) ||
                                 (bw < MIN_SIZE) || (bh < MIN_SIZE);
            if (invalid) { bx1 = x1; by1 = y1; bx2 = x2; by2 = y2; }

            const float gw = bx2 - bx1 + 1.0f;
            const float gh = by2 - by1 + 1.0f;
            const float garea = gw * gh;
            const bool gdeg = (gw == 1.0f) && (gh == 1.0f);

            float best_ov = -INFINITY;
            int best = 0;
            for (int a = 0; a < N_ROIS; ++a) {
                const float ax1 = R[a * 5 + 1], ay1 = R[a * 5 + 2];
                const float ax2 = R[a * 5 + 3], ay2 = R[a * 5 + 4];
                const float aw = ax2 - ax1 + 1.0f, ah = ay2 - ay1 + 1.0f;
                float iw = fminf(ax2, bx2) - fmaxf(ax1, bx1) + 1.0f;
                float ih = fminf(ay2, by2) - fmaxf(ay1, by1) + 1.0f;
                iw = fmaxf(iw, 0.0f);
                ih = fmaxf(ih, 0.0f);
                const float inter = iw * ih;
                float ov = inter / (aw * ah + garea - inter);
                if (gdeg) ov = 0.0f;
                if (aw == 1.0f && ah == 1.0f) ov = -1.0f;
                if (ov > best_ov) { best_ov = ov; best = a; }  // first-max tie
            }

            bool label = (best_ov >= 0.3f);
            const float w_cell = bx2 - bx1;
            const float h_cell = by2 - by1;
            const float rw = label ? (R[best * 5 + 3] - R[best * 5 + 1]) : 0.0f;
            const float rh = label ? (R[best * 5 + 4] - R[best * 5 + 2]) : 0.0f;
            label = label &&
                    !(fmaxf(rw, rh) >= fmaxf(w_cell, h_cell)) &&
                    !(fminf(rw, rh) < fminf(w_cell, h_cell) / 3.0f);
            if (label) {
                bx1 = R[best * 5 + 1]; by1 = R[best * 5 + 2];
                bx2 = R[best * 5 + 3]; by2 = R[best * 5 + 4];
            }
            if (tid == 0 && cg == 0) {
                float* row = out + OUT_POOL_ELEMS + (size_t)b * 5;
                row[0] = 0.0f;
                row[1] = bx1; row[2] = by1; row[3] = bx2; row[4] = by2;
            }
        }
        if (tid == 0) { BX[0] = bx1; BX[1] = by1; BX[2] = bx2; BX[3] = by2; }
    }
    __syncthreads();

    const float bx1 = BX[0], by1 = BX[1], bx2 = BX[2], by2 = BX[3];

    // ---- pooling geometry (all threads; wave-uniform) ----
    // jnp.round = round-half-to-even = rintf (default rounding mode)
    const float sw = rintf(bx1 * SCALE);
    const float sh = rintf(by1 * SCALE);
    const float ew = rintf(bx2 * SCALE);
    const float eh = rintf(by2 * SCALE);
    const float bsh = fmaxf(eh - sh + 1.0f, 1.0f) * (1.0f / (float)PH);
    const float bsw = fmaxf(ew - sw + 1.0f, 1.0f) * (1.0f / (float)PW);

    int wsA[PW], weA[PW];
    #pragma unroll
    for (int j = 0; j < PW; ++j) {
        wsA[j] = (int)fminf(fmaxf(floorf((float)j * bsw) + sw, 0.0f), (float)W_FEAT);
        weA[j] = (int)fminf(fmaxf(ceilf((float)(j + 1) * bsw) + sw, 0.0f), (float)W_FEAT);
    }
    const int xs = wsA[0];                                   // window col start
    const int ys = (int)fminf(fmaxf(sh, 0.0f), (float)H_FEAT); // window row start

    const int cl = tid & 63;          // local channel 0..63
    const int i  = tid >> 6;          // pooled row 0..6 (wave-uniform)
    const int c  = cg * CH_G + cl;    // global channel

    const int hs = (int)fminf(fmaxf(floorf((float)i * bsh) + sh, 0.0f), (float)H_FEAT);
    const int he = (int)fminf(fmaxf(ceilf((float)(i + 1) * bsh) + sh, 0.0f), (float)H_FEAT);

    // narrow guarantees window <= 14x14 (ceil(7*bsw)<=14, ceil(7*bsh)<=14)
    // and we[j] <= xs + 2j+2 (kmax pruning). Always true for this data.
    const bool narrow = (bsw <= 2.0f) && (bsh <= 2.0f);   // block-uniform

    float mx[PW];
    #pragma unroll
    for (int j = 0; j < PW; ++j) mx[j] = -1e30f;

    if (narrow) {
        // ---- step 3: stage 64ch x 14x14 window, NCHW -> LDS ----
        // 64*196 = 12544 = 448*28 -> exactly 28 elems/thread, no bounds check.
        #pragma unroll 4
        for (int e = tid; e < CH_G * WROWS * WCOLS; e += THREADS) {
            const int ch = e / (WROWS * WCOLS);              // const-div magic
            const int p  = e - ch * (WROWS * WCOLS);
            const int yy = p / WCOLS;
            const int xx = p - yy * WCOLS;
            const int gy = (ys + yy < H_FEAT - 1) ? (ys + yy) : (H_FEAT - 1);
            const int gx = (xs + xx < W_FEAT - 1) ? (xs + xx) : (W_FEAT - 1);
            // clamped slots are never selected by the predicates below
            win[ch * WSTRIDE + p] =
                f[(size_t)(cg * CH_G + ch) * P_FEAT + gy * W_FEAT + gx];
        }
        __syncthreads();

        // ---- step 4: proven predicated-max inner loop, from LDS ----
        for (int y = hs; y < he; ++y) {
            const int ly = y - ys;                           // 0..13
            const float* wr = win + cl * WSTRIDE + ly * WCOLS;
            float wk[WCOLS];
            #pragma unroll
            for (int k = 0; k < WCOLS; ++k) wk[k] = wr[k];   // batched, lgkm group
            #pragma unroll
            for (int j = 0; j < PW; ++j) {
                const int lo = wsA[j], hi = weA[j];
                const int kmax = (2 * j + 2 < WCOLS) ? (2 * j + 2) : WCOLS;
                #pragma unroll
                for (int k = 0; k < kmax; ++k) {
                    const int x = xs + k;
                    const bool in = (x >= lo) & (x < hi);
                    const float t = fmaxf(mx[j], wk[k]);
                    mx[j] = in ? t : mx[j];                  // v_cndmask, no branch
                }
            }
        }
    } else {
        // general fallback (not taken for this data): direct NCHW reads
        for (int y = hs; y < he; ++y) {
            const float* fr = f + (size_t)c * P_FEAT + y * W_FEAT;
            #pragma unroll
            for (int j = 0; j < PW; ++j)
                for (int x = wsA[j]; x < weA[j]; ++x)
                    mx[j] = fmaxf(mx[j], fr[x]);
        }
    }

    // ---- step 5: direct stores (round -1 pattern, measured fine) ----
    const bool rowv = (he > hs);
    float* ob = out + (size_t)b * POOL_PER_BOX + (size_t)c * CELLS + i * PW;
    #pragma unroll
    for (int j = 0; j < PW; ++j)
        ob[j] = (rowv && (weA[j] > wsA[j])) ? mx[j] : 0.0f;
}

// ---------------------------------------------------------------------------
extern "C" void kernel_launch(void* const* d_in, const int* in_sizes, int n_in,
                              void* d_out, int out_size, void* d_ws, size_t ws_size,
                              hipStream_t stream) {
    const float* features = (const float*)d_in[0];   // (1,256,40,40)
    const float* rois     = (const float*)d_in[1];   // (32,5)
    const int*   hh_p     = (const int*)d_in[2];
    const int*   hw_p     = (const int*)d_in[3];

    float* out = (float*)d_out;
    (void)d_ws; (void)ws_size; (void)in_sizes; (void)n_in; (void)out_size;

    // ONE launch, ZERO workspace use.
    hipLaunchKernelGGL(fused_pool_kernel, dim3(POOL_BLKS), dim3(THREADS), 0, stream,
                       features, rois, hh_p, hw_p, out);
}

// Round 3
// 85.088 us; speedup vs baseline: 1.1836x; 1.1836x over previous
//
#include <hip/hip_runtime.h>
#include <math.h>

// Problem constants (from reference / setup_inputs)
#define N_ROIS   32
#define N_CAT    (N_ROIS * 9)      // 288 cat_rois rows
#define C_FEAT   256
#define H_FEAT   40
#define W_FEAT   40
#define P_FEAT   (H_FEAT * W_FEAT) // 1600 pixels
#define PH       7
#define PW       7
#define SCALE    0.0625f
#define MIN_SIZE 16.0f
#define CELLS    (PH * PW)                 // 49
#define POOL_PER_BOX (C_FEAT * CELLS)      // 12544
#define OUT_POOL_ELEMS ((size_t)N_CAT * POOL_PER_BOX)  // 3,612,672

#define N_TRANS_BLOCKS (P_FEAT / 32 * (C_FEAT / 32))   // 50*8 = 400
#define CQ (C_FEAT / 4)                    // 64 channel-quads per pixel

// ---------------------------------------------------------------------------
// Kernel 0 (fused prep): blocks 0..399 transpose features (C,P)->(P,C);
// block 400 computes context anchors + IoU labeling -> cat_rois (288x5).
// (VERBATIM from the 82.4us round-0 kernel — proven correct, ~4us by model.)
// ---------------------------------------------------------------------------
__global__ void prep_kernel(const float* __restrict__ f,
                            const float* __restrict__ rois,
                            const int* __restrict__ hh_p,
                            const int* __restrict__ hw_p,
                            float* __restrict__ ft,
                            float* __restrict__ cat_out,
                            int use_transpose) {
    __shared__ float tile[32][33];   // transpose tile (+1 pad)
    __shared__ float R[N_ROIS * 5];  // rois stage for context half
    const int bid = blockIdx.x;
    const int tid = threadIdx.x;

    if (bid < N_TRANS_BLOCKS) {
        if (!use_transpose) return;
        const int pt = (bid % (P_FEAT / 32)) * 32;
        const int ct = (bid / (P_FEAT / 32)) * 32;
        const int lx = tid & 31;
        const int ly = tid >> 5;     // 0..7
        #pragma unroll
        for (int i = 0; i < 32; i += 8)
            tile[ly + i][lx] = f[(ct + ly + i) * P_FEAT + (pt + lx)];
        __syncthreads();
        #pragma unroll
        for (int i = 0; i < 32; i += 8)
            ft[(pt + ly + i) * C_FEAT + (ct + lx)] = tile[lx][ly + i];
        return;
    }

    // ---- context-anchor half (one block, 256 threads) ----
    if (tid < N_ROIS * 5) R[tid] = rois[tid];
    __syncthreads();

    const float hh = (float)(*hh_p);
    const float hw = (float)(*hw_p);

    const int g = tid;               // 0..255 -> gt box
    const int n = g >> 3;
    const int j = g & 7;
    const int m = (j < 4) ? j : j + 1;   // skip center of 3x3
    const int r  = m / 3;
    const int cc = m % 3;

    const float x1 = R[n * 5 + 1], y1 = R[n * 5 + 2];
    const float x2 = R[n * 5 + 3], y2 = R[n * 5 + 4];
    const float w = x2 - x1, h = y2 - y1;

    const float cx = x1 + w * ((float)cc - 0.5f);
    const float cy = y1 + h * ((float)r  - 0.5f);
    float bx1 = cx - w * 0.25f;
    float by1 = cy - h * 0.25f;
    float bx2 = cx + w * 0.25f;
    float by2 = cy + h * 0.25f;
    const float bw = bx2 - bx1 + 1.0f;
    const float bh = by2 - by1 + 1.0f;
    const bool invalid = (bx1 < 0.0f) || (by1 < 0.0f) ||
                         (bx2 >= hw) || (by2 >= hh) ||
                         (bw < MIN_SIZE) || (bh < MIN_SIZE);
    if (invalid) { bx1 = x1; by1 = y1; bx2 = x2; by2 = y2; }

    const float gw = bx2 - bx1 + 1.0f;
    const float gh = by2 - by1 + 1.0f;
    const float garea = gw * gh;
    const bool gdeg = (gw == 1.0f) && (gh == 1.0f);

    float best_ov = -INFINITY;
    int best = 0;
    for (int a = 0; a < N_ROIS; ++a) {
        const float ax1 = R[a * 5 + 1], ay1 = R[a * 5 + 2];
        const float ax2 = R[a * 5 + 3], ay2 = R[a * 5 + 4];
        const float aw = ax2 - ax1 + 1.0f, ah = ay2 - ay1 + 1.0f;
        float iw = fminf(ax2, bx2) - fmaxf(ax1, bx1) + 1.0f;
        float ih = fminf(ay2, by2) - fmaxf(ay1, by1) + 1.0f;
        iw = fmaxf(iw, 0.0f);
        ih = fmaxf(ih, 0.0f);
        const float inter = iw * ih;
        float ov = inter / (aw * ah + garea - inter);
        if (gdeg) ov = 0.0f;
        if (aw == 1.0f && ah == 1.0f) ov = -1.0f;
        if (ov > best_ov) { best_ov = ov; best = a; }
    }

    bool label = (best_ov >= 0.3f);
    const float w_cell = bx2 - bx1;
    const float h_cell = by2 - by1;
    const float rw = label ? (R[best * 5 + 3] - R[best * 5 + 1]) : 0.0f;
    const float rh = label ? (R[best * 5 + 4] - R[best * 5 + 2]) : 0.0f;
    label = label &&
            !(fmaxf(rw, rh) >= fmaxf(w_cell, h_cell)) &&
            !(fminf(rw, rh) < fminf(w_cell, h_cell) / 3.0f);
    if (label) {
        bx1 = R[best * 5 + 1]; by1 = R[best * 5 + 2];
        bx2 = R[best * 5 + 3]; by2 = R[best * 5 + 4];
    }

    float* row = cat_out + (size_t)(n * 9 + 1 + j) * 5;
    row[0] = 0.0f;
    row[1] = bx1; row[2] = by1; row[3] = bx2; row[4] = by2;
    if (j == 0) {
        float* rr = cat_out + (size_t)(n * 9) * 5;
        #pragma unroll
        for (int t = 0; t < 5; ++t) rr[t] = R[n * 5 + t];
    }
}

// ---------------------------------------------------------------------------
// Kernel 1 (v3): wave-uniform dynamic loops + float4 (4 channels/thread).
//
// Why: R2's counters showed ~2500 VALU inst/thread — 30x the irreducible
// fmax work — from per-lane predicate emulation (v_cmp x2 + and + fmax +
// cndmask per element) of bounds that are BLOCK-UNIFORM. Here hs/he/ws/we
// are readfirstlane'd to SGPRs and used as plain loop bounds: zero
// divergence (all lanes share the box geometry), loop control on SALU,
// inner body = 1 global_load_dwordx4 + 4 v_max_f32. No LDS, no predicates,
// no 'narrow' special case (uniform loops are fully general).
//
// Grid: 2016 blocks = (i*288+b) -> b is the fast index, so box b's 7 row
// blocks land on XCD b%8 (the round-0 mapping that graded best). 64 threads
// = 64 channel-quads; every load is one fully-coalesced 1KB dwordx4.
// ---------------------------------------------------------------------------
__global__ __launch_bounds__(64) void
roi_pool_v3(const float* __restrict__ ft,
            const float* __restrict__ cat_rois,
            float* __restrict__ out) {
    const int i = blockIdx.x / N_CAT;  // pooled row 0..6
    const int b = blockIdx.x % N_CAT;  // box 0..287 (fast -> XCD = b%8)
    const int l = threadIdx.x;         // channel-quad 0..63

    const float* cr = cat_rois + (size_t)b * 5;
    const float x1 = cr[1], y1 = cr[2], x2 = cr[3], y2 = cr[4];
    // jnp.round = round-half-to-even = rintf (default rounding mode)
    const float sw = rintf(x1 * SCALE);
    const float sh = rintf(y1 * SCALE);
    const float ew = rintf(x2 * SCALE);
    const float eh = rintf(y2 * SCALE);
    const float bsh = fmaxf(eh - sh + 1.0f, 1.0f) * (1.0f / (float)PH);
    const float bsw = fmaxf(ew - sw + 1.0f, 1.0f) * (1.0f / (float)PW);

    // block-uniform bounds -> SGPRs (scalar loop control, no divergence)
    const int hs = __builtin_amdgcn_readfirstlane(
        (int)fminf(fmaxf(floorf((float)i * bsh) + sh, 0.0f), (float)H_FEAT));
    const int he = __builtin_amdgcn_readfirstlane(
        (int)fminf(fmaxf(ceilf((float)(i + 1) * bsh) + sh, 0.0f), (float)H_FEAT));

    int ws[PW], we[PW];
    #pragma unroll
    for (int j = 0; j < PW; ++j) {
        ws[j] = __builtin_amdgcn_readfirstlane(
            (int)fminf(fmaxf(floorf((float)j * bsw) + sw, 0.0f), (float)W_FEAT));
        we[j] = __builtin_amdgcn_readfirstlane(
            (int)fminf(fmaxf(ceilf((float)(j + 1) * bsw) + sw, 0.0f), (float)W_FEAT));
    }

    float4 mx[PW];
    #pragma unroll
    for (int j = 0; j < PW; ++j)
        mx[j] = make_float4(-1e30f, -1e30f, -1e30f, -1e30f);

    for (int y = hs; y < he; ++y) {
        // pixel (y,x) holds 256 floats = 64 float4; quad l at +l
        const float4* py = (const float4*)ft + (size_t)(y * W_FEAT) * CQ + l;
        #pragma unroll
        for (int j = 0; j < PW; ++j) {
            for (int x = ws[j]; x < we[j]; ++x) {   // uniform dynamic loop
                const float4 v = py[(size_t)x * CQ];
                mx[j].x = fmaxf(mx[j].x, v.x);
                mx[j].y = fmaxf(mx[j].y, v.y);
                mx[j].z = fmaxf(mx[j].z, v.z);
                mx[j].w = fmaxf(mx[j].w, v.w);
            }
        }
    }

    const bool rowv = (he > hs);
    // thread owns channels 4l..4l+3; out[b][c][i*7+j], stride CELLS per ch
    float* ob = out + (size_t)b * POOL_PER_BOX + (size_t)(4 * l) * CELLS + i * PW;
    #pragma unroll
    for (int j = 0; j < PW; ++j) {
        const bool val = rowv && (we[j] > ws[j]);
        const float4 m = mx[j];
        ob[j]             = val ? m.x : 0.0f;
        ob[j + CELLS]     = val ? m.y : 0.0f;
        ob[j + 2 * CELLS] = val ? m.z : 0.0f;
        ob[j + 3 * CELLS] = val ? m.w : 0.0f;
    }
}

// fallback pool (untransposed layout) — only used if ws too small
__global__ __launch_bounds__(256) void
roi_pool_kernel_nchw(const float* __restrict__ feat,
                     const float* __restrict__ cat_rois,
                     float* __restrict__ out) {
    const int i = blockIdx.x / N_CAT;
    const int b = blockIdx.x % N_CAT;
    const int c = threadIdx.x;

    const float* cr = cat_rois + (size_t)b * 5;
    const float sw = rintf(cr[1] * SCALE);
    const float sh = rintf(cr[2] * SCALE);
    const float ew = rintf(cr[3] * SCALE);
    const float eh = rintf(cr[4] * SCALE);
    const float bsh = fmaxf(eh - sh + 1.0f, 1.0f) * (1.0f / (float)PH);
    const float bsw = fmaxf(ew - sw + 1.0f, 1.0f) * (1.0f / (float)PW);

    const int hs = (int)fminf(fmaxf(floorf((float)i * bsh) + sh, 0.0f), (float)H_FEAT);
    const int he = (int)fminf(fmaxf(ceilf((float)(i + 1) * bsh) + sh, 0.0f), (float)H_FEAT);
    int ws[PW], we[PW];
    #pragma unroll
    for (int j = 0; j < PW; ++j) {
        ws[j] = (int)fminf(fmaxf(floorf((float)j * bsw) + sw, 0.0f), (float)W_FEAT);
        we[j] = (int)fminf(fmaxf(ceilf((float)(j + 1) * bsw) + sw, 0.0f), (float)W_FEAT);
    }
    float mx[PW];
    #pragma unroll
    for (int j = 0; j < PW; ++j) mx[j] = -1e30f;
    for (int y = hs; y < he; ++y) {
        const float* fr = feat + (size_t)c * P_FEAT + y * W_FEAT;
        #pragma unroll
        for (int j = 0; j < PW; ++j)
            for (int x = ws[j]; x < we[j]; ++x)
                mx[j] = fmaxf(mx[j], fr[x]);
    }
    const bool rowv = (he > hs);
    float* ob = out + (size_t)b * POOL_PER_BOX + (size_t)c * CELLS + i * PW;
    #pragma unroll
    for (int j = 0; j < PW; ++j)
        ob[j] = (rowv && (we[j] > ws[j])) ? mx[j] : 0.0f;
}

// ---------------------------------------------------------------------------
extern "C" void kernel_launch(void* const* d_in, const int* in_sizes, int n_in,
                              void* d_out, int out_size, void* d_ws, size_t ws_size,
                              hipStream_t stream) {
    const float* features = (const float*)d_in[0];   // (1,256,40,40)
    const float* rois     = (const float*)d_in[1];   // (32,5)
    const int*   hh_p     = (const int*)d_in[2];
    const int*   hw_p     = (const int*)d_in[3];

    float* out      = (float*)d_out;
    float* cat_out  = out + OUT_POOL_ELEMS;          // (288,5) tail of d_out
    float* ft       = (float*)d_ws;                  // transposed features

    const size_t ft_bytes = (size_t)C_FEAT * P_FEAT * sizeof(float);
    const int use_transpose = (ws_size >= ft_bytes) ? 1 : 0;

    hipLaunchKernelGGL(prep_kernel, dim3(N_TRANS_BLOCKS + 1), dim3(256), 0, stream,
                       features, rois, hh_p, hw_p, ft, cat_out, use_transpose);

    if (use_transpose) {
        hipLaunchKernelGGL(roi_pool_v3, dim3(PH * N_CAT), dim3(64), 0, stream,
                           ft, cat_out, out);
    } else {
        hipLaunchKernelGGL(roi_pool_kernel_nchw, dim3(PH * N_CAT), dim3(C_FEAT), 0, stream,
                           features, cat_out, out);
    }
}